// Round 2
// baseline (3349.665 us; speedup 1.0000x reference)
//
#include <hip/hip_runtime.h>

#define NTOT 200000
#define EE   1200000

__global__ __launch_bounds__(256) void k_deg_init(float* deg) {
    int n = blockIdx.x*256 + threadIdx.x;
    if (n < NTOT) deg[n] = 1.0f;
}

__global__ __launch_bounds__(256) void k_deg_scatter(const float* __restrict__ ew,
                                                     const int* __restrict__ dst,
                                                     float* __restrict__ deg) {
    int e = blockIdx.x*256 + threadIdx.x;
    if (e < EE) atomicAdd(&deg[dst[e]], ew[e]);
}

__global__ __launch_bounds__(256) void k_dinv(float* deg) {
    int n = blockIdx.x*256 + threadIdx.x;
    if (n < NTOT) deg[n] = rsqrtf(deg[n]);
}

// A[n,h] = x[n]*W1[h];  B[n,h] = dinv[n]^2 * A[n,h] + b1[h]   (self-loop folded in)
__global__ __launch_bounds__(256) void k_xw1(const float* __restrict__ x,
                                             const float* __restrict__ W1,
                                             const float* __restrict__ b1,
                                             const float* __restrict__ dinv,
                                             float* __restrict__ A,
                                             float* __restrict__ B) {
    int i = blockIdx.x*256 + threadIdx.x;
    if (i >= NTOT*64) return;
    int n = i >> 6, hh = i & 63;
    float t = x[n] * W1[hh];
    float di = dinv[n];
    A[i] = t;
    B[i] = di*di*t + b1[hh];
}

// B[dst,:] += dinv[src]*ew*dinv[dst] * A[src,:]   — 16 lanes per edge, float4 gather
__global__ __launch_bounds__(256) void k_scatter(const int* __restrict__ src,
                                                 const int* __restrict__ dst,
                                                 const float* __restrict__ ew,
                                                 const float* __restrict__ dinv,
                                                 const float* __restrict__ A,
                                                 float* __restrict__ B) {
    unsigned long long t = (unsigned long long)blockIdx.x*256ull + threadIdx.x;
    int e = (int)(t >> 4);
    if (e >= EE) return;
    int q = ((int)t & 15) << 2;
    int s = src[e], d = dst[e];
    float norm = dinv[s] * ew[e] * dinv[d];
    const float4 v = *(const float4*)(A + (size_t)s*64 + q);
    float* bp = B + (size_t)d*64 + q;
    atomicAdd(bp+0, norm*v.x);
    atomicAdd(bp+1, norm*v.y);
    atomicAdd(bp+2, norm*v.z);
    atomicAdd(bp+3, norm*v.w);
}

// y1 = relu(B-row); xw2 = y1 @ W2; A-row = xw2; B-row = dinv^2*xw2 + b2
// thread-per-node; weight indices are loop-uniform -> scalar (s_load) path
__global__ __launch_bounds__(256) void k_gcn2(float* __restrict__ A,
                                              float* __restrict__ B,
                                              const float* __restrict__ dinv,
                                              const float* __restrict__ W2,
                                              const float* __restrict__ b2) {
    int n = blockIdx.x*256 + threadIdx.x;
    if (n >= NTOT) return;
    float y[64];
    {
        const float4* brow = (const float4*)(B + (size_t)n*64);
        #pragma unroll
        for (int k4 = 0; k4 < 16; ++k4) {
            float4 v = brow[k4];
            y[4*k4+0] = fmaxf(v.x, 0.f);
            y[4*k4+1] = fmaxf(v.y, 0.f);
            y[4*k4+2] = fmaxf(v.z, 0.f);
            y[4*k4+3] = fmaxf(v.w, 0.f);
        }
    }
    float di = dinv[n];
    float d2 = di*di;
    float4* arow = (float4*)(A + (size_t)n*64);
    float4* brow = (float4*)(B + (size_t)n*64);
    #pragma unroll 1
    for (int c4 = 0; c4 < 16; ++c4) {
        float ax=0.f, ay=0.f, az=0.f, aw=0.f;
        #pragma unroll
        for (int k = 0; k < 64; ++k) {
            const float* wr = W2 + k*64 + c4*4;   // uniform address
            ax += y[k]*wr[0];
            ay += y[k]*wr[1];
            az += y[k]*wr[2];
            aw += y[k]*wr[3];
        }
        float4 xw; xw.x=ax; xw.y=ay; xw.z=az; xw.w=aw;
        arow[c4] = xw;
        float4 bb;
        bb.x = d2*ax + b2[c4*4+0];
        bb.y = d2*ay + b2[c4*4+1];
        bb.z = d2*az + b2[c4*4+2];
        bb.w = d2*aw + b2[c4*4+3];
        brow[c4] = bb;
    }
}

// y2 = relu(B-row); GRUCell; out = h_new @ fc_w + fc_b; hnew written to d_out tail
__global__ __launch_bounds__(256) void k_gru(const float* __restrict__ B,
                                             const float* __restrict__ h_in,
                                             const float* __restrict__ wih,
                                             const float* __restrict__ whh,
                                             const float* __restrict__ bih,
                                             const float* __restrict__ bhh,
                                             const float* __restrict__ fcw,
                                             const float* __restrict__ fcb,
                                             float* __restrict__ out,
                                             float* __restrict__ hnew) {
    int n = blockIdx.x*256 + threadIdx.x;
    if (n >= NTOT) return;
    float y[64], hv[64];
    {
        const float4* brow = (const float4*)(B + (size_t)n*64);
        const float4* hrow = (const float4*)(h_in + (size_t)n*64);
        #pragma unroll
        for (int k4 = 0; k4 < 16; ++k4) {
            float4 v = brow[k4];
            y[4*k4+0]=fmaxf(v.x,0.f); y[4*k4+1]=fmaxf(v.y,0.f);
            y[4*k4+2]=fmaxf(v.z,0.f); y[4*k4+3]=fmaxf(v.w,0.f);
            float4 w = hrow[k4];
            hv[4*k4+0]=w.x; hv[4*k4+1]=w.y; hv[4*k4+2]=w.z; hv[4*k4+3]=w.w;
        }
    }
    float po0=0.f,po1=0.f,po2=0.f,po3=0.f,po4=0.f;
    #pragma unroll 1
    for (int l = 0; l < 64; ++l) {
        float ar = bih[l], az = bih[64+l], an = bih[128+l];
        float gr = bhh[l], gz = bhh[64+l], gn = bhh[128+l];
        const float* wr0 = wih + l*64;        // all uniform addresses -> s_load
        const float* wr1 = wih + (64+l)*64;
        const float* wr2 = wih + (128+l)*64;
        const float* vr0 = whh + l*64;
        const float* vr1 = whh + (64+l)*64;
        const float* vr2 = whh + (128+l)*64;
        #pragma unroll
        for (int k = 0; k < 64; ++k) {
            ar += y[k]*wr0[k];
            az += y[k]*wr1[k];
            an += y[k]*wr2[k];
            gr += hv[k]*vr0[k];
            gz += hv[k]*vr1[k];
            gn += hv[k]*vr2[k];
        }
        float r  = 1.f/(1.f + expf(-(ar+gr)));
        float z  = 1.f/(1.f + expf(-(az+gz)));
        float nn = tanhf(an + r*gn);
        // avoid runtime-indexing the hv register array (scratch trap): reload from global
        float hfl = h_in[(size_t)n*64 + l];
        float hnv = (1.f - z)*nn + z*hfl;
        hnew[(size_t)n*64 + l] = hnv;
        const float* fr = fcw + l*5;          // uniform
        po0 += hnv*fr[0]; po1 += hnv*fr[1]; po2 += hnv*fr[2];
        po3 += hnv*fr[3]; po4 += hnv*fr[4];
    }
    float* op = out + (size_t)n*5;
    op[0]=po0+fcb[0]; op[1]=po1+fcb[1]; op[2]=po2+fcb[2];
    op[3]=po3+fcb[3]; op[4]=po4+fcb[4];
}

extern "C" void kernel_launch(void* const* d_in, const int* in_sizes, int n_in,
                              void* d_out, int out_size, void* d_ws, size_t ws_size,
                              hipStream_t stream) {
    const float* x   = (const float*)d_in[0];
    const float* ew  = (const float*)d_in[1];
    const float* h   = (const float*)d_in[2];
    const float* W1  = (const float*)d_in[3];
    const float* b1  = (const float*)d_in[4];
    const float* W2  = (const float*)d_in[5];
    const float* b2  = (const float*)d_in[6];
    const float* wih = (const float*)d_in[7];
    const float* whh = (const float*)d_in[8];
    const float* bih = (const float*)d_in[9];
    const float* bhh = (const float*)d_in[10];
    const float* fcw = (const float*)d_in[11];
    const float* fcb = (const float*)d_in[12];
    const int*   ei  = (const int*)d_in[13];
    const int* src = ei;
    const int* dst = ei + EE;

    float* out  = (float*)d_out;
    // Reuse d_out's h_new region (N*64 floats) as the gather-source buffer A:
    // last read of A is scatter #2; k_gru then overwrites it with h_new.
    float* A    = out + (size_t)NTOT*5;
    float* dinv = (float*)d_ws;
    float* B    = (float*)((char*)d_ws + (1<<20));   // ws usage: 1MB + 51.2MB

    k_deg_init   <<<(NTOT+255)/256,          256, 0, stream>>>(dinv);
    k_deg_scatter<<<(EE+255)/256,            256, 0, stream>>>(ew, dst, dinv);
    k_dinv       <<<(NTOT+255)/256,          256, 0, stream>>>(dinv);
    k_xw1        <<<(NTOT*64+255)/256,       256, 0, stream>>>(x, W1, b1, dinv, A, B);
    k_scatter    <<<((EE*16)+255)/256,       256, 0, stream>>>(src, dst, ew, dinv, A, B);
    k_gcn2       <<<(NTOT+255)/256,          256, 0, stream>>>(A, B, dinv, W2, b2);
    k_scatter    <<<((EE*16)+255)/256,       256, 0, stream>>>(src, dst, ew, dinv, A, B);
    k_gru        <<<(NTOT+255)/256,          256, 0, stream>>>(B, h, wih, whh, bih, bhh,
                                                               fcw, fcb, out, A);
}